// Round 6
// baseline (232.522 us; speedup 1.0000x reference)
//
#include <hip/hip_runtime.h>
#include <stdint.h>

#define NSK 1000
#define TT  200
#define BB  64
#define NB  256            // grid blocks (1 per CU -> co-resident, safe for grid barrier)
#define NROW (BB * TT)     // 12800
#define NOUT (BB * (TT-1)) // 12736
#define NPAIR (NOUT / 2)   // 6368
#define CH  8              // scan pipeline depth (steps)
#define RW  8              // scan Mv rows per wave

__device__ __forceinline__ float lane_bcast(float v, int l) {
  return __uint_as_float(__builtin_amdgcn_readlane(__float_as_uint(v), l));
}
__device__ __forceinline__ float frcp(float x) { return __builtin_amdgcn_rcpf(x); }
__device__ __forceinline__ float sigm(float x) { return frcp(1.f + __expf(-x)); }
__device__ __forceinline__ float tanh_fast(float x) {
  return fmaf(-2.f, frcp(1.f + __expf(2.f * x)), 1.f);   // 1 - 2/(1+e^2x)
}

// device-scope grid barrier: all NB blocks co-resident (1 block/CU).
// release-fence + agent atomic arrive; spin (thread 0 only) + acquire-fence.
__device__ __forceinline__ void grid_barrier(unsigned* cnt) {
  __syncthreads();
  if (threadIdx.x == 0) {
    __threadfence();
    __hip_atomic_fetch_add(cnt, 1u, __ATOMIC_ACQ_REL, __HIP_MEMORY_SCOPE_AGENT);
    while (__hip_atomic_load(cnt, __ATOMIC_ACQUIRE, __HIP_MEMORY_SCOPE_AGENT) < NB)
      __builtin_amdgcn_s_sleep(2);
    __threadfence();
  }
  __syncthreads();
}

// ---- scan helpers (unchanged algorithm: register double-buffer, no __syncthreads) ----
__device__ __forceinline__ void load_chunk(
    const float* __restrict__ wr, const float* __restrict__ er,
    const float* __restrict__ ar, int t0, int wl, int lane,
    float* wb, float* ebf, float* abf)
{
  #pragma unroll
  for (int k = 0; k < CH; ++k) {
    wb[k]  = wr[(t0 + k) * 64 + wl];
    ebf[k] = er[(t0 + k) * 64 + lane];
    abf[k] = ar[(t0 + k) * 64 + lane];
  }
}

__device__ __forceinline__ void compute_chunk(
    float* Mv, const float* wb, const float* ebf, const float* abf,
    int t0, int part, int lane, float* __restrict__ pr)
{
  #pragma unroll
  for (int k = 0; k < CH; ++k) {
    const float wv = wb[k], ev = ebf[k], av = abf[k];
    float rp = 0.f;
    #pragma unroll
    for (int i = 0; i < RW; ++i) {
      float wm = lane_bcast(wv, i);        // w[m0+i] sits in lane i (0..7)
      rp = fmaf(wm, Mv[i], rp);            // read uses PRE-update Mv
      float tp = fmaf(-ev, Mv[i], av);     // a - e*Mv
      Mv[i] = fmaf(wm, tp, Mv[i]);         // Mv += w*(a - e*Mv)
    }
    pr[(t0 + k) * 512 + part * 64 + lane] = rp;
  }
}

__global__ __launch_bounds__(256, 1) void dkvmn_fused(
    const int* __restrict__ skills, const int* __restrict__ responses,
    const float* __restrict__ k_emb, const float* __restrict__ v_emb,
    const float* __restrict__ Mk, const float* __restrict__ Mv0,
    const float* __restrict__ fW, const float* __restrict__ fb,
    const float* __restrict__ eW, const float* __restrict__ eb,
    const float* __restrict__ aW, const float* __restrict__ ab,
    const float* __restrict__ pW, const float* __restrict__ pb,
    unsigned* __restrict__ cnt,
    float* __restrict__ w_ws, float* __restrict__ e_ws, float* __restrict__ a_ws,
    float* __restrict__ part_ws, float* __restrict__ out)
{
  __shared__ float smem[12288];            // 48 KB: phase A = Mk|eW|aW, phase C = fW
  const int tid  = threadIdx.x;
  const int wave = tid >> 6, lane = tid & 63;
  const int gw   = blockIdx.x * 4 + wave;  // global wave id, 0..1023

  // ---------------- Phase A: w = softmax(k Mk^T), e = sigm(v eW^T+eb), a = tanh(v aW^T+ab)
  for (int Q = tid; Q < 1024; Q += 256) {  // stage 3x 64x64 with quad-rotation swizzle
    const int j = Q >> 4, c = Q & 15;
    const int dst = j * 64 + ((c + j) & 15) * 4;
    *(float4*)&smem[dst]        = ((const float4*)Mk)[Q];
    *(float4*)&smem[4096 + dst] = ((const float4*)eW)[Q];
    *(float4*)&smem[8192 + dst] = ((const float4*)aW)[Q];
  }
  __syncthreads();
  {
    const float ebl = eb[lane], abl = ab[lane];
    // 2-deep gather pipeline: indices 1 row ahead of k/v, k/v 1 row ahead of compute
    int r = gw;
    int sk0 = skills[r];
    int rr0 = responses[r]; rr0 = (rr0 > -1) ? rr0 : 0;
    int r1 = r + 1024;
    int sk1 = 0, rr1 = 0;
    if (r1 < NROW) { sk1 = skills[r1]; rr1 = responses[r1]; rr1 = (rr1 > -1) ? rr1 : 0; }
    float kv = k_emb[(size_t)sk0 * 64 + lane];
    float vv = v_emb[(size_t)(sk0 + NSK * rr0) * 64 + lane];

    for (; r < NROW; r += 1024) {
      const int rn = r + 1024;
      float kvn = 0.f, vvn = 0.f;
      int sk2 = 0, rr2 = 0;
      if (rn < NROW) {
        kvn = k_emb[(size_t)sk1 * 64 + lane];
        vvn = v_emb[(size_t)(sk1 + NSK * rr1) * 64 + lane];
        const int rn2 = rn + 1024;
        if (rn2 < NROW) { sk2 = skills[rn2]; rr2 = responses[rn2]; rr2 = (rr2 > -1) ? rr2 : 0; }
      }
      float accK = 0.f, accE = 0.f, accA = 0.f;
      #pragma unroll
      for (int c = 0; c < 16; ++c) {
        const int off = lane * 64 + ((c + lane) & 15) * 4;
        float4 qm = *(const float4*)&smem[off];
        float4 qe = *(const float4*)&smem[4096 + off];
        float4 qa = *(const float4*)&smem[8192 + off];
        const float mm[4] = {qm.x, qm.y, qm.z, qm.w};
        const float ee[4] = {qe.x, qe.y, qe.z, qe.w};
        const float aa[4] = {qa.x, qa.y, qa.z, qa.w};
        #pragma unroll
        for (int j = 0; j < 4; ++j) {
          const int d = c * 4 + j;
          const float kd = lane_bcast(kv, d);
          const float vd = lane_bcast(vv, d);
          accK = fmaf(kd, mm[j], accK);
          accE = fmaf(vd, ee[j], accE);
          accA = fmaf(vd, aa[j], accA);
        }
      }
      float mx = accK;
      #pragma unroll
      for (int off = 32; off; off >>= 1) mx = fmaxf(mx, __shfl_xor(mx, off));
      float ex = __expf(accK - mx);
      float sm = ex;
      #pragma unroll
      for (int off = 32; off; off >>= 1) sm += __shfl_xor(sm, off);
      w_ws[(size_t)r * 64 + lane] = ex * frcp(sm);
      e_ws[(size_t)r * 64 + lane] = sigm(accE + ebl);
      a_ws[(size_t)r * 64 + lane] = tanh_fast(accA + abl);
      kv = kvn; vv = vvn; sk1 = sk2; rr1 = rr2;
    }
  }

  grid_barrier(&cnt[0]);

  // ---------------- Phase B: sequential scan on blocks 0..127 (2 blocks/batch, 8 rows/wave)
  if (blockIdx.x < 2 * BB) {
    const int b  = blockIdx.x >> 1, s = blockIdx.x & 1;
    const int m0 = s * 32 + wave * RW;
    const int part = s * 4 + wave;
    const int wl = m0 + (lane & (RW - 1));
    float Mv[RW];
    #pragma unroll
    for (int i = 0; i < RW; ++i) Mv[i] = Mv0[(size_t)(m0 + i) * 64 + lane];

    const float* wr = w_ws + (size_t)b * TT * 64;
    const float* er = e_ws + (size_t)b * TT * 64;
    const float* ar = a_ws + (size_t)b * TT * 64;
    float* pr = part_ws + (size_t)b * TT * 512;

    float wb0[CH], eb0[CH], ab0[CH];
    float wb1[CH], eb1[CH], ab1[CH];
    load_chunk(wr, er, ar, 0, wl, lane, wb0, eb0, ab0);
    for (int ch = 0; ch < TT / CH; ch += 2) {
      if ((ch + 1) * CH < TT)
        load_chunk(wr, er, ar, (ch + 1) * CH, wl, lane, wb1, eb1, ab1);
      compute_chunk(Mv, wb0, eb0, ab0, ch * CH, part, lane, pr);
      if ((ch + 2) * CH < TT)
        load_chunk(wr, er, ar, (ch + 2) * CH, wl, lane, wb0, eb0, ab0);
      if ((ch + 1) * CH < TT)
        compute_chunk(Mv, wb1, eb1, ab1, (ch + 1) * CH, part, lane, pr);
    }
  }

  grid_barrier(&cnt[1]);

  // ---------------- Phase C: read = sum 8 partials; f = tanh([read,k] fW^T + fb); p = sigm(f pW + pb)
  for (int Q = tid; Q < 2048; Q += 256) {  // restage fW (64x128) into the same LDS
    const int j = Q >> 5, c = Q & 31;
    *(float4*)&smem[j * 128 + ((c + j) & 31) * 4] = ((const float4*)fW)[Q];
  }
  __syncthreads();
  {
    const float fbl = fb[lane], pwl = pW[lane], pb0 = pb[0];
    // pairs of rows share register-cached fW quarters; 1-pair-ahead prefetch
    float pc[2][8], kc[2];
    int p = gw;
    {
      #pragma unroll
      for (int h = 0; h < 2; ++h) {
        const unsigned idx = 2u * p + h;
        const unsigned b = idx / 199u;
        const int row = (int)(idx + b + 1u);
        const float* pp = part_ws + (size_t)row * 512;
        #pragma unroll
        for (int q = 0; q < 8; ++q) pc[h][q] = pp[q * 64 + lane];
        kc[h] = k_emb[(size_t)skills[row] * 64 + lane];
      }
    }
    for (; p < NPAIR; p += 1024) {
      const int pn = p + 1024;
      float pn_[2][8], kn_[2];
      if (pn < NPAIR) {
        #pragma unroll
        for (int h = 0; h < 2; ++h) {
          const unsigned idx = 2u * pn + h;
          const unsigned b = idx / 199u;
          const int row = (int)(idx + b + 1u);
          const float* pp = part_ws + (size_t)row * 512;
          #pragma unroll
          for (int q = 0; q < 8; ++q) pn_[h][q] = pp[q * 64 + lane];
          kn_[h] = k_emb[(size_t)skills[row] * 64 + lane];
        }
      }
      float rv0 = ((pc[0][0] + pc[0][1]) + (pc[0][2] + pc[0][3]))
                + ((pc[0][4] + pc[0][5]) + (pc[0][6] + pc[0][7]));
      float rv1 = ((pc[1][0] + pc[1][1]) + (pc[1][2] + pc[1][3]))
                + ((pc[1][4] + pc[1][5]) + (pc[1][6] + pc[1][7]));
      const float kv0 = kc[0], kv1 = kc[1];
      float acc0 = fbl, acc1 = fbl;
      #pragma unroll 1
      for (int h = 0; h < 2; ++h) {        // first 64 inputs: read vector
        float4 qf[8];
        #pragma unroll
        for (int c = 0; c < 8; ++c) {
          const int cc = h * 8 + c;
          qf[c] = *(const float4*)&smem[lane * 128 + ((cc + lane) & 31) * 4];
        }
        #pragma unroll
        for (int c = 0; c < 8; ++c) {
          const float ww[4] = {qf[c].x, qf[c].y, qf[c].z, qf[c].w};
          #pragma unroll
          for (int j = 0; j < 4; ++j) {
            const int d = h * 32 + c * 4 + j;
            acc0 = fmaf(lane_bcast(rv0, d), ww[j], acc0);
            acc1 = fmaf(lane_bcast(rv1, d), ww[j], acc1);
          }
        }
      }
      #pragma unroll 1
      for (int h = 0; h < 2; ++h) {        // last 64 inputs: k vector
        float4 qf[8];
        #pragma unroll
        for (int c = 0; c < 8; ++c) {
          const int cc = (h + 2) * 8 + c;
          qf[c] = *(const float4*)&smem[lane * 128 + ((cc + lane) & 31) * 4];
        }
        #pragma unroll
        for (int c = 0; c < 8; ++c) {
          const float ww[4] = {qf[c].x, qf[c].y, qf[c].z, qf[c].w};
          #pragma unroll
          for (int j = 0; j < 4; ++j) {
            const int d = h * 32 + c * 4 + j;
            acc0 = fmaf(lane_bcast(kv0, d), ww[j], acc0);
            acc1 = fmaf(lane_bcast(kv1, d), ww[j], acc1);
          }
        }
      }
      float f0 = tanh_fast(acc0) * pwl;
      float f1 = tanh_fast(acc1) * pwl;
      #pragma unroll
      for (int off = 32; off; off >>= 1) {
        f0 += __shfl_xor(f0, off);
        f1 += __shfl_xor(f1, off);
      }
      if (lane == 0) {
        out[2 * p]     = sigm(f0 + pb0);
        out[2 * p + 1] = sigm(f1 + pb0);
      }
      #pragma unroll
      for (int h = 0; h < 2; ++h) {
        #pragma unroll
        for (int q = 0; q < 8; ++q) pc[h][q] = pn_[h][q];
        kc[h] = kn_[h];
      }
    }
  }
}

extern "C" void kernel_launch(void* const* d_in, const int* in_sizes, int n_in,
                              void* d_out, int out_size, void* d_ws, size_t ws_size,
                              hipStream_t stream) {
  const int* skills    = (const int*)d_in[0];
  const int* responses = (const int*)d_in[1];
  const float* k_emb   = (const float*)d_in[2];
  const float* v_emb   = (const float*)d_in[3];
  const float* Mk      = (const float*)d_in[4];
  const float* Mv0     = (const float*)d_in[5];
  const float* fW      = (const float*)d_in[6];
  const float* fb      = (const float*)d_in[7];
  const float* eW      = (const float*)d_in[8];
  const float* eb      = (const float*)d_in[9];
  const float* aW      = (const float*)d_in[10];
  const float* ab      = (const float*)d_in[11];
  const float* pW      = (const float*)d_in[12];
  const float* pb      = (const float*)d_in[13];

  // ws layout: [0,256) barrier counters (zeroed every call) | w | e | a | partials  (~36 MB)
  unsigned* cnt  = (unsigned*)d_ws;
  float* base    = (float*)d_ws + 64;
  float* w_ws    = base;
  float* e_ws    = w_ws + (size_t)BB * TT * 64;
  float* a_ws    = e_ws + (size_t)BB * TT * 64;
  float* part_ws = a_ws + (size_t)BB * TT * 64;

  hipMemsetAsync(d_ws, 0, 256, stream);
  dkvmn_fused<<<dim3(NB), dim3(256), 0, stream>>>(
      skills, responses, k_emb, v_emb, Mk, Mv0, fW, fb, eW, eb, aW, ab, pW, pb,
      cnt, w_ws, e_ws, a_ws, part_ws, (float*)d_out);
}

// Round 7
// 152.018 us; speedup vs baseline: 1.5296x; 1.5296x over previous
//
#include <hip/hip_runtime.h>
#include <hip/hip_bf16.h>
#include <stdint.h>

#define NSK 1000
#define TT  200
#define BB  64
#define NROW (BB * TT)      // 12800
#define NOUT (BB * (TT-1))  // 12736
#define CH  8               // scan pipeline depth (steps)
#define RW  8               // scan Mv rows per wave

__device__ __forceinline__ float lane_bcast(float v, int l) {
  return __uint_as_float(__builtin_amdgcn_readlane(__float_as_uint(v), l));
}
__device__ __forceinline__ float bflo(unsigned u){ return __uint_as_float(u << 16); }
__device__ __forceinline__ float bfhi(unsigned u){ return __uint_as_float(u & 0xffff0000u); }
__device__ __forceinline__ unsigned pack2(float a, float b) {
  __hip_bfloat16 ha = __float2bfloat16(a), hb = __float2bfloat16(b);
  return (unsigned)*(unsigned short*)&ha | ((unsigned)*(unsigned short*)&hb << 16);
}
__device__ __forceinline__ float frcp(float x) { return __builtin_amdgcn_rcpf(x); }
__device__ __forceinline__ float sigm(float x) { return frcp(1.f + __expf(-x)); }
__device__ __forceinline__ float tanh_fast(float x) {
  return fmaf(-2.f, frcp(1.f + __expf(2.f * x)), 1.f);   // 1 - 2/(1+e^2x)
}

// Pass A: w = softmax(k Mk^T), e = sigm(v eW^T+eb), a = tanh(v aW^T+ab), one wave per 2 rows.
// Weights bf16-packed in LDS, padded row stride 40 dwords (32 data + 8 pad):
// chunk cc of row j at dword j*40 + ((cc+j)&7)*4 -> ds_read_b128 hits the 32-bank floor exactly.
// 30 KB LDS -> 5 blocks/CU co-resident; grid 1600 blocks for TLP latency hiding.
__global__ __launch_bounds__(256) void wea_kernel(
    const int* __restrict__ skills, const int* __restrict__ responses,
    const float* __restrict__ k_emb, const float* __restrict__ v_emb,
    const float* __restrict__ Mk, const float* __restrict__ eW,
    const float* __restrict__ eb, const float* __restrict__ aW,
    const float* __restrict__ ab,
    float* __restrict__ w_ws, float* __restrict__ e_ws, float* __restrict__ a_ws)
{
  __shared__ unsigned sw[3 * 64 * 40];               // 30720 B
  const int tid = threadIdx.x;
  for (int ch = tid; ch < 1536; ch += 256) {         // 512 chunks per matrix
    const int mat = ch >> 9;
    const int rem = ch & 511;
    const int j = rem >> 3, cc = rem & 7;
    const float4* src = (mat == 0) ? (const float4*)Mk
                      : (mat == 1) ? (const float4*)eW : (const float4*)aW;
    const float4 f0 = src[j * 16 + cc * 2];
    const float4 f1 = src[j * 16 + cc * 2 + 1];
    uint4 pk;
    pk.x = pack2(f0.x, f0.y); pk.y = pack2(f0.z, f0.w);
    pk.z = pack2(f1.x, f1.y); pk.w = pack2(f1.z, f1.w);
    *(uint4*)&sw[mat * 2560 + j * 40 + ((cc + j) & 7) * 4] = pk;
  }
  __syncthreads();

  const int wave = tid >> 6, lane = tid & 63;
  const float ebl = eb[lane], abl = ab[lane];

  // 2 rows per wave; gather chains issued up-front
  const int r0 = (blockIdx.x * 4 + wave) * 2;        // grid exact: 1600*4*2 = 12800
  float kv[2], vv[2];
  #pragma unroll
  for (int i = 0; i < 2; ++i) {
    const int sk = skills[r0 + i];
    int rr = responses[r0 + i]; rr = (rr > -1) ? rr : 0;   // masked_r
    kv[i] = k_emb[(size_t)sk * 64 + lane];
    vv[i] = v_emb[(size_t)(sk + NSK * rr) * 64 + lane];
  }

  float accK[2] = {0.f, 0.f}, accE[2] = {0.f, 0.f}, accA[2] = {0.f, 0.f};
  #pragma unroll 1
  for (int h = 0; h < 2; ++h) {                      // halves: 4 chunks (32 dims) each
    uint4 qm[4], qe[4], qa[4];                       // 48 VGPR live
    #pragma unroll
    for (int c = 0; c < 4; ++c) {
      const int off = lane * 40 + (((h * 4 + c) + lane) & 7) * 4;
      qm[c] = *(const uint4*)&sw[off];
      qe[c] = *(const uint4*)&sw[2560 + off];
      qa[c] = *(const uint4*)&sw[5120 + off];
    }
    #pragma unroll
    for (int i = 0; i < 2; ++i) {
      #pragma unroll
      for (int c = 0; c < 4; ++c) {
        const unsigned um[4] = {qm[c].x, qm[c].y, qm[c].z, qm[c].w};
        const unsigned ue[4] = {qe[c].x, qe[c].y, qe[c].z, qe[c].w};
        const unsigned ua[4] = {qa[c].x, qa[c].y, qa[c].z, qa[c].w};
        #pragma unroll
        for (int m = 0; m < 4; ++m) {
          const int d0 = (h * 4 + c) * 8 + 2 * m;
          const float k0 = lane_bcast(kv[i], d0), k1 = lane_bcast(kv[i], d0 + 1);
          const float v0 = lane_bcast(vv[i], d0), v1 = lane_bcast(vv[i], d0 + 1);
          accK[i] = fmaf(k0, bflo(um[m]), accK[i]);
          accK[i] = fmaf(k1, bfhi(um[m]), accK[i]);
          accE[i] = fmaf(v0, bflo(ue[m]), accE[i]);
          accE[i] = fmaf(v1, bfhi(ue[m]), accE[i]);
          accA[i] = fmaf(v0, bflo(ua[m]), accA[i]);
          accA[i] = fmaf(v1, bfhi(ua[m]), accA[i]);
        }
      }
    }
  }

  #pragma unroll
  for (int i = 0; i < 2; ++i) {
    const int row = r0 + i;
    float mx = accK[i];
    #pragma unroll
    for (int off = 32; off; off >>= 1) mx = fmaxf(mx, __shfl_xor(mx, off));
    float ex = __expf(accK[i] - mx);
    float sm = ex;
    #pragma unroll
    for (int off = 32; off; off >>= 1) sm += __shfl_xor(sm, off);
    w_ws[(size_t)row * 64 + lane] = ex * frcp(sm);
    e_ws[(size_t)row * 64 + lane] = sigm(accE[i] + ebl);
    a_ws[(size_t)row * 64 + lane] = tanh_fast(accA[i] + abl);
  }
}

// ---- scan helpers: chunked register double-buffer (depth CH=8 steps) ----
__device__ __forceinline__ void load_chunk(
    const float* __restrict__ wr, const float* __restrict__ er,
    const float* __restrict__ ar, int t0, int wl, int lane,
    float* wb, float* ebf, float* abf)
{
  #pragma unroll
  for (int k = 0; k < CH; ++k) {
    wb[k]  = wr[(t0 + k) * 64 + wl];
    ebf[k] = er[(t0 + k) * 64 + lane];
    abf[k] = ar[(t0 + k) * 64 + lane];
  }
}

__device__ __forceinline__ void compute_chunk(
    float* Mv, const float* wb, const float* ebf, const float* abf,
    int t0, int part, int lane, float* __restrict__ pr)
{
  #pragma unroll
  for (int k = 0; k < CH; ++k) {
    const float wv = wb[k], ev = ebf[k], av = abf[k];
    float rp = 0.f;
    #pragma unroll
    for (int i = 0; i < RW; ++i) {
      float wm = lane_bcast(wv, i);        // w[m0+i] sits in lane i (0..7)
      rp = fmaf(wm, Mv[i], rp);            // read uses PRE-update Mv
      float tp = fmaf(-ev, Mv[i], av);     // a - e*Mv
      Mv[i] = fmaf(wm, tp, Mv[i]);         // Mv += w*(a - e*Mv)
    }
    pr[(t0 + k) * 512 + part * 64 + lane] = rp;
  }
}

// Pass B: sequential scan; Mv rows independent -> 2 blocks x 4 waves x 8 rows per batch.
__global__ __launch_bounds__(256) void scan_kernel(
    const float* __restrict__ Mv0,
    const float* __restrict__ w_ws, const float* __restrict__ e_ws,
    const float* __restrict__ a_ws, float* __restrict__ part_ws)
{
  const int b    = blockIdx.x >> 1;
  const int s    = blockIdx.x & 1;
  const int wave = threadIdx.x >> 6;
  const int lane = threadIdx.x & 63;
  const int m0   = s * 32 + wave * RW;
  const int part = s * 4 + wave;
  const int wl   = m0 + (lane & (RW - 1));
  float Mv[RW];
  #pragma unroll
  for (int i = 0; i < RW; ++i) Mv[i] = Mv0[(size_t)(m0 + i) * 64 + lane];

  const float* wr = w_ws + (size_t)b * TT * 64;
  const float* er = e_ws + (size_t)b * TT * 64;
  const float* ar = a_ws + (size_t)b * TT * 64;
  float* pr = part_ws + (size_t)b * TT * 512;

  float wb0[CH], eb0[CH], ab0[CH];
  float wb1[CH], eb1[CH], ab1[CH];
  load_chunk(wr, er, ar, 0, wl, lane, wb0, eb0, ab0);
  for (int ch = 0; ch < TT / CH; ch += 2) {
    if ((ch + 1) * CH < TT)
      load_chunk(wr, er, ar, (ch + 1) * CH, wl, lane, wb1, eb1, ab1);
    compute_chunk(Mv, wb0, eb0, ab0, ch * CH, part, lane, pr);
    if ((ch + 2) * CH < TT)
      load_chunk(wr, er, ar, (ch + 2) * CH, wl, lane, wb0, eb0, ab0);
    if ((ch + 1) * CH < TT)
      compute_chunk(Mv, wb1, eb1, ab1, (ch + 1) * CH, part, lane, pr);
  }
}

// Pass C: read = sum 8 partials; f = tanh([read,k] fW^T + fb); p = sigm(f pW + pb).
// fW bf16-packed in LDS, row stride 72 dwords (64 data + 8 pad), chunk rotation mod 16.
// 18 KB LDS; 2 rows/wave; grid 1592 blocks.
__global__ __launch_bounds__(256) void fp_kernel(
    const int* __restrict__ skills, const float* __restrict__ k_emb,
    const float* __restrict__ fW, const float* __restrict__ fb,
    const float* __restrict__ pW, const float* __restrict__ pb,
    const float* __restrict__ part_ws, float* __restrict__ out)
{
  __shared__ unsigned sf[64 * 72];                   // 18432 B
  const int tid = threadIdx.x;
  for (int ch = tid; ch < 1024; ch += 256) {         // 16 chunks per row
    const int j = ch >> 4, cc = ch & 15;
    const float4 f0 = ((const float4*)fW)[j * 32 + cc * 2];
    const float4 f1 = ((const float4*)fW)[j * 32 + cc * 2 + 1];
    uint4 pk;
    pk.x = pack2(f0.x, f0.y); pk.y = pack2(f0.z, f0.w);
    pk.z = pack2(f1.x, f1.y); pk.w = pack2(f1.z, f1.w);
    *(uint4*)&sf[j * 72 + ((cc + j) & 15) * 4] = pk;
  }
  __syncthreads();

  const int wave = tid >> 6, lane = tid & 63;
  const float fbl = fb[lane], pwl = pW[lane], pb0 = pb[0];

  const int p = blockIdx.x * 4 + wave;               // pair id, grid exact: 1592*4 = 6368
  // both rows' loads issued up-front (16 partial loads + 2 gathers)
  float pc[2][8], kc[2];
  int bsave[2], tsave[2];
  #pragma unroll
  for (int i = 0; i < 2; ++i) {
    const unsigned idx = 2u * p + i;
    const unsigned b = idx / 199u;
    const int row = (int)(idx + b + 1u);
    bsave[i] = (int)b; tsave[i] = (int)(idx - b * 199u);
    const float* pp = part_ws + (size_t)row * 512;
    #pragma unroll
    for (int q = 0; q < 8; ++q) pc[i][q] = pp[q * 64 + lane];
    kc[i] = k_emb[(size_t)skills[row] * 64 + lane];
  }
  float rv[2];
  #pragma unroll
  for (int i = 0; i < 2; ++i)
    rv[i] = ((pc[i][0] + pc[i][1]) + (pc[i][2] + pc[i][3]))
          + ((pc[i][4] + pc[i][5]) + (pc[i][6] + pc[i][7]));

  float acc[2] = {fbl, fbl};
  #pragma unroll 1
  for (int h = 0; h < 4; ++h) {                      // quarters: 4 chunks (32 inputs) each
    uint4 qf[4];                                     // 16 VGPR live
    #pragma unroll
    for (int c = 0; c < 4; ++c)
      qf[c] = *(const uint4*)&sf[lane * 72 + (((h * 4 + c) + lane) & 15) * 4];
    #pragma unroll
    for (int i = 0; i < 2; ++i) {
      const float src = 0.f; (void)src;
      #pragma unroll
      for (int c = 0; c < 4; ++c) {
        const unsigned uu[4] = {qf[c].x, qf[c].y, qf[c].z, qf[c].w};
        #pragma unroll
        for (int m = 0; m < 4; ++m) {
          const int d0 = (h * 4 + c) * 8 + 2 * m;    // 0..126
          const float s0 = (d0 < 64) ? lane_bcast(rv[i], d0) : lane_bcast(kc[i], d0 - 64);
          const float s1 = (d0 + 1 < 64) ? lane_bcast(rv[i], d0 + 1) : lane_bcast(kc[i], d0 - 63);
          acc[i] = fmaf(s0, bflo(uu[m]), acc[i]);
          acc[i] = fmaf(s1, bfhi(uu[m]), acc[i]);
        }
      }
    }
  }

  float f0 = tanh_fast(acc[0]) * pwl;
  float f1 = tanh_fast(acc[1]) * pwl;
  #pragma unroll
  for (int off = 32; off; off >>= 1) {
    f0 += __shfl_xor(f0, off);
    f1 += __shfl_xor(f1, off);
  }
  if (lane == 0) {
    out[(size_t)bsave[0] * (TT - 1) + tsave[0]] = sigm(f0 + pb0);
    out[(size_t)bsave[1] * (TT - 1) + tsave[1]] = sigm(f1 + pb0);
  }
}

extern "C" void kernel_launch(void* const* d_in, const int* in_sizes, int n_in,
                              void* d_out, int out_size, void* d_ws, size_t ws_size,
                              hipStream_t stream) {
  const int* skills    = (const int*)d_in[0];
  const int* responses = (const int*)d_in[1];
  const float* k_emb   = (const float*)d_in[2];
  const float* v_emb   = (const float*)d_in[3];
  const float* Mk      = (const float*)d_in[4];
  const float* Mv0     = (const float*)d_in[5];
  const float* fW      = (const float*)d_in[6];
  const float* fb      = (const float*)d_in[7];
  const float* eW      = (const float*)d_in[8];
  const float* eb      = (const float*)d_in[9];
  const float* aW      = (const float*)d_in[10];
  const float* ab      = (const float*)d_in[11];
  const float* pW      = (const float*)d_in[12];
  const float* pb      = (const float*)d_in[13];

  // fp32 scratch: w | e | a (B*T*64 each) | read-partials (B*T*512) ~= 36 MB
  float* w_ws    = (float*)d_ws;
  float* e_ws    = w_ws + (size_t)BB * TT * 64;
  float* a_ws    = e_ws + (size_t)BB * TT * 64;
  float* part_ws = a_ws + (size_t)BB * TT * 64;

  wea_kernel<<<dim3(NROW / 8), 256, 0, stream>>>(
      skills, responses, k_emb, v_emb, Mk, eW, eb, aW, ab, w_ws, e_ws, a_ws);
  scan_kernel<<<dim3(BB * 2), 256, 0, stream>>>(Mv0, w_ws, e_ws, a_ws, part_ws);
  fp_kernel<<<dim3(NOUT / 8), 256, 0, stream>>>(
      skills, k_emb, fW, fb, pW, pb, part_ws, (float*)d_out);
}